// Round 4
// baseline (292.678 us; speedup 1.0000x reference)
//
#include <hip/hip_runtime.h>

// Reference numpy/jnp math is UNFUSED IEEE f32 — disable FMA contraction so
// the catastrophically-cancelled det (compared against EPS=1e-7) and the
// 1/det-scaled shifts are bit-identical to the reference.
#pragma clang fp contract(off)

// Problem constants (from setup_inputs): B=2, C=4, D=6, H=512, W=512, f32.
constexpr int B_ = 2, C_ = 4, D_ = 6, H_ = 512, W_ = 512;
constexpr int HW_  = H_ * W_;        // 262144
constexpr int DHW_ = D_ * HW_;       // 1572864
constexpr int BC_  = B_ * C_;        // 8
constexpr int TOT_ = BC_ * DHW_;     // 12582912

#define EPS_ 1e-7f
#define MAX_SHIFT_ 0.6f
#define BONUS_ 10.0f
#define N_ITERS_ 5

// Clang native vectors — accepted by __builtin_nontemporal_store (HIP's
// float4 is a struct and is rejected).
typedef float f32x4 __attribute__((ext_vector_type(4)));
typedef int   i32x4 __attribute__((ext_vector_type(4)));

// ---------------------------------------------------------------------------
// 3x3x3 quadratic-fit Cramer solve; p points at the (interior) center voxel.
// Op ordering mirrors the reference exactly (f32, no contraction).
__device__ __forceinline__ void solve3(const float* __restrict__ p,
                                       float& sx, float& sy, float& ss,
                                       float& gds, bool& sol)
{
    #pragma clang fp contract(off)
    float c    = p[0];
    float xp   = p[1],          xm   = p[-1];
    float yp   = p[W_],         ym   = p[-W_];
    float spv  = p[HW_],        smv  = p[-HW_];
    float xpyp = p[W_ + 1],     xmyp = p[W_ - 1];
    float xpym = p[-W_ + 1],    xmym = p[-W_ - 1];
    float xpsp = p[HW_ + 1],    xmsp = p[HW_ - 1];
    float xpsm = p[-HW_ + 1],   xmsm = p[-HW_ - 1];
    float ypsp = p[HW_ + W_],   ymsp = p[HW_ - W_];
    float ypsm = p[-HW_ + W_],  ymsm = p[-HW_ - W_];

    float gx = 0.5f * (xp - xm);
    float gy = 0.5f * (yp - ym);
    float gs = 0.5f * (spv - smv);
    float dxx = xp - 2.0f * c + xm;
    float dyy = yp - 2.0f * c + ym;
    float dss = spv - 2.0f * c + smv;
    float dxy = 0.25f * (xpyp - xmyp - xpym + xmym);
    float dxs = 0.25f * (xpsp - xmsp - xpsm + xmsm);
    float dys = 0.25f * (ypsp - ymsp - ypsm + ymsm);

    float cf00 = dyy * dss - dys * dys;
    float cf01 = dxy * dss - dys * dxs;
    float cf02 = dxy * dys - dyy * dxs;
    float det  = dxx * cf00 - dxy * cf01 + dxs * cf02;
    sol = fabsf(det) > EPS_;
    float sd = sol ? det : 1.0f;
    float r0 = -gx, r1 = -gy, r2 = -gs;
    sx = (r0 * cf00 - dxy * (r1 * dss - dys * r2) + dxs * (r1 * dys - dyy * r2)) / sd;
    sy = (dxx * (r1 * dss - dys * r2) - r0 * cf01 + dxs * (dxy * r2 - r1 * dxs)) / sd;
    ss = (dxx * (dyy * r2 - r1 * dys) - dxy * (dxy * r2 - r1 * dxs) + r0 * cf02) / sd;
    gds = gx * sx + gy * sy + gs * ss;
}

// ---------------------------------------------------------------------------
// One fused pass, one thread per EIGHT consecutive-w voxels (W=512 % 8 == 0,
// all 8 share bc,d,h). Streaming path is fully decoupled from the walk:
//   load 2x f32x4 x + 2x i32x4 mask (2 KB/wave bursts per stream),
//   store ALL default outputs immediately (8x nt dwordx4 — no dependence on
//   the walk), then the rare (0.1%) seed lanes walk and overwrite their 4
//   scalars (same thread, same address → program-order safe).
__global__ __launch_bounds__(256)
void AdaptiveQuadInterp3d_kernel(const float* __restrict__ x,
                                 const int* __restrict__ mask,
                                 float* __restrict__ out)
{
    int tid = blockIdx.x * 256 + threadIdx.x;
    int e   = tid * 8;                 // first voxel of this thread's group

    int w0 = e & (W_ - 1);             // multiple of 8
    int h  = (e >> 9) & (H_ - 1);
    int t  = e >> 18;                  // bc*D + d   (HW = 2^18)
    int d  = t % D_;
    int bc = t / D_;
    int sp = e - bc * DHW_;

    const f32x4 xa = *reinterpret_cast<const f32x4*>(x + e);
    const f32x4 xbv = *reinterpret_cast<const f32x4*>(x + e + 4);
    const i32x4 ma = *reinterpret_cast<const i32x4*>(mask + e);
    const i32x4 mb = *reinterpret_cast<const i32x4*>(mask + e + 4);

    // ---- Default outputs: stream out NOW, no walk dependence. -------------
    float fd = (float)d, fh = (float)h;
    float* cb = out + (bc * 3) * DHW_ + sp;           // cs stream
    float* yb = out + BC_ * 3 * DHW_ + e;             // y stream

    f32x4 csv = { fd, fd, fd, fd };
    f32x4 cxa = { (float)w0,       (float)(w0 + 1),
                  (float)(w0 + 2), (float)(w0 + 3) };
    f32x4 cxb = { (float)(w0 + 4), (float)(w0 + 5),
                  (float)(w0 + 6), (float)(w0 + 7) };
    f32x4 cyv = { fh, fh, fh, fh };

    __builtin_nontemporal_store(csv, reinterpret_cast<f32x4*>(cb));
    __builtin_nontemporal_store(csv, reinterpret_cast<f32x4*>(cb + 4));
    __builtin_nontemporal_store(cxa, reinterpret_cast<f32x4*>(cb + DHW_));
    __builtin_nontemporal_store(cxb, reinterpret_cast<f32x4*>(cb + DHW_ + 4));
    __builtin_nontemporal_store(cyv, reinterpret_cast<f32x4*>(cb + 2 * DHW_));
    __builtin_nontemporal_store(cyv, reinterpret_cast<f32x4*>(cb + 2 * DHW_ + 4));
    __builtin_nontemporal_store(xa,  reinterpret_cast<f32x4*>(yb));
    __builtin_nontemporal_store(xbv, reinterpret_cast<f32x4*>(yb + 4));

    int anym = ma.x | ma.y | ma.z | ma.w | mb.x | mb.y | mb.z | mb.w;

    // Rare path: walk each seed component, overwrite its 4 output scalars.
    if (__ballot(anym != 0) != 0ULL) {
        if (anym != 0) {
            const float* xbase = x + bc * DHW_;

            auto walk = [&](int mj, int j, float xc) {
                #pragma clang fp contract(off)
                if (mj == 0) return;
                int w = w0 + j;
                int dsd = 0, dsh = 0, dsw = 0;
                bool valid = true;
                float shx = 0.0f, shy = 0.0f, shs = 0.0f, gk = 0.0f;

                // Exact early termination:
                //  - !sol → valid false forever, outputs are defaults (+BONUS on y).
                //  - valid with all-zero steps = fixed point: later iterations
                //    recompute identical values. Bit-exact vs reference.
                #pragma unroll 1
                for (int it = 0; it < N_ITERS_; ++it) {
                    int di = min(max(d + dsd, 1), D_ - 2);
                    int hi = min(max(h + dsh, 1), H_ - 2);
                    int wi = min(max(w + dsw, 1), W_ - 2);
                    const float* p = xbase + di * HW_ + hi * W_ + wi;

                    float sx, sy, ssv, gds; bool sol;
                    solve3(p, sx, sy, ssv, gds, sol);

                    if (!sol) { valid = false; break; }

                    shx = sx; shy = sy; shs = ssv; gk = gds;

                    int stx = (shx > MAX_SHIFT_) ? 1 : ((shx < -MAX_SHIFT_) ? -1 : 0);
                    int sty = (shy > MAX_SHIFT_) ? 1 : ((shy < -MAX_SHIFT_) ? -1 : 0);
                    int sts = (shs > MAX_SHIFT_) ? 1 : ((shs < -MAX_SHIFT_) ? -1 : 0);
                    dsw += stx;
                    dsh += sty;
                    dsd += sts;
                    valid = (abs(dsd) <= 1) && (abs(dsh) <= 1) && (abs(dsw) <= 1);
                    if (!valid) break;                  // radius breach — exact
                    if ((stx | sty | sts) == 0) break;  // fixed point — exact
                }

                if (valid) {
                    int di = min(max(d + dsd, 1), D_ - 2);
                    int hi = min(max(h + dsh, 1), H_ - 2);
                    int wi = min(max(w + dsw, 1), W_ - 2);
                    float cur = xbase[di * HW_ + hi * W_ + wi];
                    __builtin_nontemporal_store((float)(d + dsd) + shs, cb + j);
                    __builtin_nontemporal_store((float)(w + dsw) + shx, cb + DHW_ + j);
                    __builtin_nontemporal_store((float)(h + dsh) + shy, cb + 2 * DHW_ + j);
                    __builtin_nontemporal_store((cur + 0.5f * gk) + BONUS_, yb + j);
                } else {
                    // Coord defaults already stored; only y changes.
                    __builtin_nontemporal_store(xc + BONUS_, yb + j);
                }
            };

            walk(ma.x, 0, xa.x);
            walk(ma.y, 1, xa.y);
            walk(ma.z, 2, xa.z);
            walk(ma.w, 3, xa.w);
            walk(mb.x, 4, xbv.x);
            walk(mb.y, 5, xbv.y);
            walk(mb.z, 6, xbv.z);
            walk(mb.w, 7, xbv.w);
        }
    }
}

extern "C" void kernel_launch(void* const* d_in, const int* in_sizes, int n_in,
                              void* d_out, int out_size, void* d_ws, size_t ws_size,
                              hipStream_t stream) {
    const float* x    = (const float*)d_in[0];
    const int*   mask = (const int*)d_in[1];
    float*       out  = (float*)d_out;

    int blocks = TOT_ / (256 * 8);   // 6144
    AdaptiveQuadInterp3d_kernel<<<blocks, 256, 0, stream>>>(x, mask, out);
}